// Round 2
// baseline (616.840 us; speedup 1.0000x reference)
//
#include <hip/hip_runtime.h>
#include <hip/hip_bf16.h>

// Flash attention fwd, 1 head, B=64, S=1024, D=256.
// Inputs/outputs fp32 (per reference); compute in bf16 MFMA, fp32 accum.
// A bf16-I/O variant is kept as insurance; on-device dtype detection picks
// one, the other exits immediately (graph-capture-safe, same work each call).
//
// R2: occupancy/latency attack.
//  - BQ=128, 8 waves (512 thr): one staged KV tile feeds 2x the q rows;
//    staging work, KV fetch, and barriers halve per output. 2 blocks/CU
//    -> 16 waves/CU (~47% occupancy) for phase overlap.
//  - LDS = exactly 80 KB/block (2x = full 160 KB pool): pads replaced by
//    granule XOR-swizzle (granule ^= row&7) on ks and ps; all b128
//    reads/writes remain 8-slot permutations (conflict-free), including
//    vs-build column reads.
//  - Defer-rescale: skip the 256 acc mults + exp2 per tile unless the
//    running row-max grew > THRU (wave-uniform branch). P <= 2^2.7, safe.
//  - Grid (batch, qtile): linear id = batch + 64*qtile -> all 8 blocks of
//    a batch land on one XCD (id%8) for KV L2 reuse.

#define NB   64
#define NQ   1024
#define NKV  1024
#define DM   256
#define BQ   128    // q rows per block (8 waves x 16)
#define BK   64     // kv rows per tile
#define NTHR 512
#define LOG2E   1.4426950408889634f
#define SCL     (0.0625f * LOG2E)   // fold scale=256^-0.5 into exp2 arg
#define NEG_BIG (-1e30f)            // finite "-inf"
#define THRU    30.0f               // defer-rescale threshold (unscaled); P <= 2^(30*SCL)=6.5

typedef __attribute__((ext_vector_type(8))) short  bf16x8;   // 8 bf16 = 4 VGPRs
typedef __attribute__((ext_vector_type(4))) float  floatx4;

__device__ __forceinline__ ushort f2bf(float f) {
  __hip_bfloat16 h = __float2bfloat16(f);
  return *(ushort*)&h;
}

// flag=1: data is bf16; flag=0: data is fp32.
__global__ void detect_dtype(const unsigned int* __restrict__ q,
                             int* __restrict__ flag) {
  __shared__ int cnt;
  if (threadIdx.x == 0) cnt = 0;
  __syncthreads();
  unsigned int w = q[(size_t)threadIdx.x * 32003u];
  unsigned int e = (w >> 7) & 0xFFu;
  int good = (e >= 96u && e < 160u) ? 1 : 0;
  atomicAdd(&cnt, good);
  __syncthreads();
  if (threadIdx.x == 0) flag[0] = (cnt > 192) ? 1 : 0;
}

template <bool IS_BF16>
__global__ __launch_bounds__(NTHR, 4) void attn_fwd(
    const void* __restrict__ qv, const void* __restrict__ kvv,
    void* __restrict__ outv, const int* __restrict__ flag)
{
  if (flag[0] != (IS_BF16 ? 1 : 0)) return;   // block-uniform: barrier-safe

  // ks: kv tile, row-major, granule-XOR-swizzled: elem(row,k) at
  //     (row<<8) + (((k>>3) ^ (row&7))<<3) + (k&7)              (32 KB)
  // vs: granule-transposed V copy (granule = 8 kv of one d), slot-rotated:
  //     granule(d,kc) at (d>>3)*1024 + (d&7)*128 + ((kc+d)&7)*16 (32 KB)
  // ps: per-wave P staging, swizzled like ks with row stride 64  (16 KB)
  __shared__ ushort ks[BK * DM];
  __shared__ ushort vs[BK * DM];
  __shared__ ushort ps[8 * 16 * 64];

  const int tid   = threadIdx.x;
  const int wave  = tid >> 6;
  const int lane  = tid & 63;
  const int quad  = lane >> 4;
  const int l16   = lane & 15;
  const int batch = blockIdx.x;          // id%8 == batch%8 -> same-XCD KV share
  const int q0    = blockIdx.y * BQ + wave * 16;

  // Q fragments, A-layout: a[j] = Q[m=l16][k = kb*32 + quad*8 + j]
  bf16x8 qf[8];
  if constexpr (IS_BF16) {
    const ushort* qp = (const ushort*)qv + ((size_t)(batch * NQ + q0 + l16)) * DM + quad * 8;
#pragma unroll
    for (int kb = 0; kb < 8; ++kb)
      qf[kb] = *(const bf16x8*)(qp + kb * 32);
  } else {
    const float* qp = (const float*)qv + ((size_t)(batch * NQ + q0 + l16)) * DM + quad * 8;
#pragma unroll
    for (int kb = 0; kb < 8; ++kb) {
      float4 f0 = *(const float4*)(qp + kb * 32);
      float4 f1 = *(const float4*)(qp + kb * 32 + 4);
      bf16x8 o; ushort* op = (ushort*)&o;
      op[0]=f2bf(f0.x); op[1]=f2bf(f0.y); op[2]=f2bf(f0.z); op[3]=f2bf(f0.w);
      op[4]=f2bf(f1.x); op[5]=f2bf(f1.y); op[6]=f2bf(f1.z); op[7]=f2bf(f1.w);
      qf[kb] = o;
    }
  }

  floatx4 acc[16];                // O acc, C-layout: acc[nt][r] = O[quad*4+r][nt*16+l16]
#pragma unroll
  for (int i = 0; i < 16; ++i) acc[i] = (floatx4){0.f, 0.f, 0.f, 0.f};
  float m_i[4] = {NEG_BIG, NEG_BIG, NEG_BIG, NEG_BIG};   // UNSCALED running max
  float l_i[4] = {0.f, 0.f, 0.f, 0.f};

  // PV read bases (loop-invariant): d = nt*16 + l16
  const int dlo = l16 & 7;
  const ushort* vb0 = vs + ((l16 >> 3) << 9) + (dlo << 6);
  const int sl0 = ((quad + dlo) & 7) << 3;        // kf=0 : kc = quad
  const int sl1 = ((quad + 4 + dlo) & 7) << 3;    // kf=1 : kc = quad+4

  for (int kt = 0; kt < NKV / BK; ++kt) {
    __syncthreads();  // protect ks/vs/ps from previous iteration's readers
    // ---- stage kv tile 64x256 into LDS as bf16 (swizzled granules) ----
    if constexpr (IS_BF16) {
      const ushort* src = (const ushort*)kvv + ((size_t)batch * NKV + kt * BK) * DM;
#pragma unroll
      for (int i = 0; i < 4; ++i) {
        int v = tid + i * NTHR;     // 2048 vec8 granules
        int r = v >> 5;             // 32 granules per row
        int cg = v & 31;
        *(bf16x8*)&ks[(r << 8) + ((cg ^ (r & 7)) << 3)] =
            *(const bf16x8*)&src[r * DM + (cg << 3)];
      }
    } else {
      const float* src = (const float*)kvv + ((size_t)batch * NKV + kt * BK) * DM;
#pragma unroll
      for (int i = 0; i < 4; ++i) {
        int v = tid + i * NTHR;
        int r = v >> 5;
        int cg = v & 31;
        const float* sp = src + r * DM + (cg << 3);
        float4 f0 = *(const float4*)(sp);
        float4 f1 = *(const float4*)(sp + 4);
        bf16x8 o; ushort* op = (ushort*)&o;
        op[0]=f2bf(f0.x); op[1]=f2bf(f0.y); op[2]=f2bf(f0.z); op[3]=f2bf(f0.w);
        op[4]=f2bf(f1.x); op[5]=f2bf(f1.y); op[6]=f2bf(f1.z); op[7]=f2bf(f1.w);
        *(bf16x8*)&ks[(r << 8) + ((cg ^ (r & 7)) << 3)] = o;
      }
    }
    __syncthreads();

    // ---- S = Q @ K^T (unscaled) : 16x64 per wave ----
    // b[j] = K[n=nt*16+l16][k=kb*32+quad*8+j]  (row-major read == A*B^T trick)
    floatx4 s[4];
#pragma unroll
    for (int nt = 0; nt < 4; ++nt) {
      floatx4 a = (floatx4){0.f, 0.f, 0.f, 0.f};
#pragma unroll
      for (int kb = 0; kb < 8; ++kb) {
        int row = nt * 16 + l16;
        bf16x8 bfr = *(const bf16x8*)&ks[(row << 8) + ((((kb << 2) + quad) ^ (row & 7)) << 3)];
        a = __builtin_amdgcn_mfma_f32_16x16x32_bf16(qf[kb], bfr, a, 0, 0, 0);
      }
      s[nt] = a;
    }

    // ---- build granule-transposed V copy: 2 threads per column d ----
    {
      const int col = tid & 255;
      const int cg  = col >> 3;
      const int c7  = col & 7;
      ushort* colp  = vs + ((col >> 3) << 9) + ((col & 7) << 6);
      const int rot = col & 7;
      const int g0  = (tid >> 8) << 2;      // threads 0-255: g 0-3; 256-511: g 4-7
#pragma unroll
      for (int gg = 0; gg < 4; ++gg) {
        int g = g0 + gg;
        bf16x8 o; ushort* op = (ushort*)&o;
#pragma unroll
        for (int i = 0; i < 8; ++i)
          op[i] = ks[((g * 8 + i) << 8) + ((cg ^ i) << 3) + c7];
        *(bf16x8*)&colp[((g + rot) & 7) << 3] = o;
      }
    }

    // ---- online softmax with deferred rescale ----
    float mx4[4];
#pragma unroll
    for (int r = 0; r < 4; ++r) {
      float mx = fmaxf(fmaxf(s[0][r], s[1][r]), fmaxf(s[2][r], s[3][r]));
      mx = fmaxf(mx, __shfl_xor(mx, 1));
      mx = fmaxf(mx, __shfl_xor(mx, 2));
      mx = fmaxf(mx, __shfl_xor(mx, 4));
      mx = fmaxf(mx, __shfl_xor(mx, 8));
      mx4[r] = mx;
    }
    float grow = fmaxf(fmaxf(mx4[0] - m_i[0], mx4[1] - m_i[1]),
                       fmaxf(mx4[2] - m_i[2], mx4[3] - m_i[3]));
    if (__any(grow > THRU)) {
#pragma unroll
      for (int r = 0; r < 4; ++r) {
        float mnew  = fmaxf(m_i[r], mx4[r]);
        float alpha = exp2f(fmaxf((m_i[r] - mnew) * SCL, -126.f));
        l_i[r] *= alpha;
        m_i[r]  = mnew;
#pragma unroll
        for (int nt = 0; nt < 16; ++nt) acc[nt][r] *= alpha;
      }
    }
    float pv[4][4];  // [nt][r]
#pragma unroll
    for (int r = 0; r < 4; ++r) {
      float rs = 0.f;
#pragma unroll
      for (int nt = 0; nt < 4; ++nt) {
        float p = exp2f((s[nt][r] - m_i[r]) * SCL);
        pv[nt][r] = p;
        rs += p;
      }
      rs += __shfl_xor(rs, 1);
      rs += __shfl_xor(rs, 2);
      rs += __shfl_xor(rs, 4);
      rs += __shfl_xor(rs, 8);
      l_i[r] += rs;
    }

    // ---- P: C-layout regs -> LDS (swizzled) -> A-layout frags ----
    ushort* pw = ps + (wave << 10);
#pragma unroll
    for (int nt = 0; nt < 4; ++nt)
#pragma unroll
      for (int r = 0; r < 4; ++r) {
        int row = quad * 4 + r;
        int cgp = nt * 2 + (l16 >> 3);
        pw[(row << 6) + ((cgp ^ (row & 7)) << 3) + (l16 & 7)] = f2bf(pv[nt][r]);
      }
    __syncthreads();   // ps ready AND vs fully built

    bf16x8 pf[2];
#pragma unroll
    for (int kf = 0; kf < 2; ++kf)
      pf[kf] = *(const bf16x8*)&pw[(l16 << 6) + ((((kf << 2) + quad) ^ (l16 & 7)) << 3)];

    // ---- O += P @ V : b[j] = V[k=kf*32+quad*8+j][n=nt*16+l16] via vs b128 ----
#pragma unroll
    for (int nt = 0; nt < 16; ++nt) {
      const ushort* vb = vb0 + (nt << 10);
      bf16x8 v0 = *(const bf16x8*)(vb + sl0);
      acc[nt] = __builtin_amdgcn_mfma_f32_16x16x32_bf16(pf[0], v0, acc[nt], 0, 0, 0);
      bf16x8 v1 = *(const bf16x8*)(vb + sl1);
      acc[nt] = __builtin_amdgcn_mfma_f32_16x16x32_bf16(pf[1], v1, acc[nt], 0, 0, 0);
    }
  }

  // ---- epilogue: O / l, store in the REFERENCE dtype ----
#pragma unroll
  for (int r = 0; r < 4; ++r) l_i[r] = 1.f / l_i[r];
  if constexpr (IS_BF16) {
    ushort* ob = (ushort*)outv + ((size_t)(batch * NQ + q0 + quad * 4)) * DM + l16;
#pragma unroll
    for (int nt = 0; nt < 16; ++nt)
#pragma unroll
      for (int r = 0; r < 4; ++r)
        ob[(size_t)r * DM + nt * 16] = f2bf(acc[nt][r] * l_i[r]);
  } else {
    float* ob = (float*)outv + ((size_t)(batch * NQ + q0 + quad * 4)) * DM + l16;
#pragma unroll
    for (int nt = 0; nt < 16; ++nt)
#pragma unroll
      for (int r = 0; r < 4; ++r)
        ob[(size_t)r * DM + nt * 16] = acc[nt][r] * l_i[r];
  }
}

extern "C" void kernel_launch(void* const* d_in, const int* in_sizes, int n_in,
                              void* d_out, int out_size, void* d_ws, size_t ws_size,
                              hipStream_t stream) {
  const void* q  = d_in[0];
  const void* kv = d_in[1];
  int* flag      = (int*)d_ws;

  detect_dtype<<<dim3(1), dim3(256), 0, stream>>>((const unsigned int*)q, flag);

  dim3 grid(NB, NQ / BQ);   // x=batch: all q-tiles of a batch share an XCD
  attn_fwd<true ><<<grid, dim3(NTHR), 0, stream>>>(q, kv, d_out, flag);
  attn_fwd<false><<<grid, dim3(NTHR), 0, stream>>>(q, kv, d_out, flag);
}

// Round 3
// 300.968 us; speedup vs baseline: 2.0495x; 2.0495x over previous
//
#include <hip/hip_runtime.h>
#include <hip/hip_bf16.h>

// Flash attention fwd, 1 head, B=64, S=1024, D=256.
// Inputs/outputs fp32 (per reference); compute in bf16 MFMA, fp32 accum.
// Dual-dtype insurance kept, now as ONE kernel with a block-uniform branch.
// Block = 256 thr (4 waves); each block: one (batch, 64-row Q tile).
//
// R3: DS-pipe-issue attack (R1 model: ~194 DS ops/thread/tile saturate the
// per-CU LDS pipe; MFMA 9% / VALU 18% / HBM 15% all idle waiting on it).
//  - softmax reductions via DPP (quad_perm xor1/xor2 + row_ror:4/8): the
//    32 ds_swizzle shuffles/tile become VALU ops (DS pipe: -32).
//  - vs-build reads ks as dword row-pairs (ds_read2-fusable, 528B apart),
//    repacks halves with integer VALU, writes b128 (72 DS -> ~24-40).
//  - defer-rescale (verified in R2): skip acc rescale unless row-max grew.
//  - vs slot rotation ((d>>1)+kc)&7 keeps even-d b128 writes AND PV reads
//    on 8 distinct bank slots (conflict-free).
// R2 lesson: 512-thr blocks forced a 128-VGPR budget -> spill -> 270MB of
// scratch writes. Geometry stays 256 thr, __launch_bounds__(256,2).

#define NB   64
#define NQ   1024
#define NKV  1024
#define DM   256
#define BQ   64     // q rows per block
#define BK   64     // kv rows per tile
#define KPAD 264    // ks row stride (elems): 528B; b128 reads 2-way (free)
#define PPAD 72     // p_lds row stride (elems): 144B, 16B-aligned
#define LOG2E   1.4426950408889634f
#define SCL     (0.0625f * LOG2E)   // fold scale=256^-0.5 into exp2 arg
#define NEG_BIG (-1e30f)            // finite "-inf"
#define THRU    30.0f               // defer threshold: P <= 2^(30*SCL) ~ 6.5

typedef __attribute__((ext_vector_type(8))) short  bf16x8;   // 8 bf16 = 4 VGPRs
typedef __attribute__((ext_vector_type(4))) float  floatx4;

__device__ __forceinline__ ushort f2bf(float f) {
  __hip_bfloat16 h = __float2bfloat16(f);
  return *(ushort*)&h;
}

// DPP lane-move within 16-lane rows (VALU pipe, no DS).
template <int CTRL>
__device__ __forceinline__ float dpp_mov(float x) {
  return __int_as_float(__builtin_amdgcn_update_dpp(
      0, __float_as_int(x), CTRL, 0xF, 0xF, false));
}
// Full 16-lane reductions; every lane ends with the row result.
__device__ __forceinline__ float red16_max(float x) {
  x = fmaxf(x, dpp_mov<0xB1>(x));    // quad_perm [1,0,3,2]  (xor 1)
  x = fmaxf(x, dpp_mov<0x4E>(x));    // quad_perm [2,3,0,1]  (xor 2)
  x = fmaxf(x, dpp_mov<0x124>(x));   // row_ror:4
  x = fmaxf(x, dpp_mov<0x128>(x));   // row_ror:8
  return x;
}
__device__ __forceinline__ float red16_sum(float x) {
  x += dpp_mov<0xB1>(x);
  x += dpp_mov<0x4E>(x);
  x += dpp_mov<0x124>(x);
  x += dpp_mov<0x128>(x);
  return x;
}

// vs granule address (elems): granule = 8 consecutive kv of one d.
__device__ __forceinline__ int vsoff(int d, int kc) {
  return ((d >> 3) << 9) + ((d & 7) << 6) + ((((d >> 1) + kc) & 7) << 3);
}

// flag=1: data is bf16; flag=0: data is fp32.
__global__ void detect_dtype(const unsigned int* __restrict__ q,
                             int* __restrict__ flag) {
  __shared__ int cnt;
  if (threadIdx.x == 0) cnt = 0;
  __syncthreads();
  unsigned int w = q[(size_t)threadIdx.x * 32003u];
  unsigned int e = (w >> 7) & 0xFFu;
  int good = (e >= 96u && e < 160u) ? 1 : 0;
  atomicAdd(&cnt, good);
  __syncthreads();
  if (threadIdx.x == 0) flag[0] = (cnt > 192) ? 1 : 0;
}

template <bool IS_BF16>
__device__ __forceinline__ void attn_body(
    const void* __restrict__ qv, const void* __restrict__ kvv,
    void* __restrict__ outv, ushort* ks, ushort* vs, ushort* ps)
{
  const int tid   = threadIdx.x;
  const int wave  = tid >> 6;
  const int lane  = tid & 63;
  const int quad  = lane >> 4;
  const int l16   = lane & 15;
  const int batch = blockIdx.y;
  const int q0    = blockIdx.x * BQ + wave * 16;

  // Q fragments, A-layout: a[j] = Q[m=l16][k = kb*32 + quad*8 + j]
  bf16x8 qf[8];
  if constexpr (IS_BF16) {
    const ushort* qp = (const ushort*)qv + ((size_t)(batch * NQ + q0 + l16)) * DM + quad * 8;
#pragma unroll
    for (int kb = 0; kb < 8; ++kb)
      qf[kb] = *(const bf16x8*)(qp + kb * 32);
  } else {
    const float* qp = (const float*)qv + ((size_t)(batch * NQ + q0 + l16)) * DM + quad * 8;
#pragma unroll
    for (int kb = 0; kb < 8; ++kb) {
      float4 f0 = *(const float4*)(qp + kb * 32);
      float4 f1 = *(const float4*)(qp + kb * 32 + 4);
      bf16x8 o; ushort* op = (ushort*)&o;
      op[0]=f2bf(f0.x); op[1]=f2bf(f0.y); op[2]=f2bf(f0.z); op[3]=f2bf(f0.w);
      op[4]=f2bf(f1.x); op[5]=f2bf(f1.y); op[6]=f2bf(f1.z); op[7]=f2bf(f1.w);
      qf[kb] = o;
    }
  }

  floatx4 acc[16];                // O acc, C-layout: acc[nt][r] = O[quad*4+r][nt*16+l16]
#pragma unroll
  for (int i = 0; i < 16; ++i) acc[i] = (floatx4){0.f, 0.f, 0.f, 0.f};
  float m_i[4] = {NEG_BIG, NEG_BIG, NEG_BIG, NEG_BIG};   // UNSCALED running max
  float l_i[4] = {0.f, 0.f, 0.f, 0.f};

  // PV read bases (loop-invariant): d = nt*16 + l16
  const int vbase = ((l16 >> 3) << 9) + ((l16 & 7) << 6);
  const int sl0 = ((quad     + (l16 >> 1)) & 7) << 3;   // kf=0 : kc = quad
  const int sl1 = ((quad + 4 + (l16 >> 1)) & 7) << 3;   // kf=1 : kc = quad+4

  for (int kt = 0; kt < NKV / BK; ++kt) {
    __syncthreads();  // protect ks/vs/ps from previous iteration's readers
    // ---- stage kv tile 64x256 into LDS as bf16 (row-major, KPAD) ----
    if constexpr (IS_BF16) {
      const ushort* src = (const ushort*)kvv + ((size_t)batch * NKV + kt * BK) * DM;
#pragma unroll
      for (int i = 0; i < 8; ++i) {
        int v = tid + i * 256;      // 2048 vec8 chunks
        int r = v >> 5;             // 32 vec8 per row
        int c = (v & 31) << 3;
        *(bf16x8*)&ks[r * KPAD + c] = *(const bf16x8*)&src[r * DM + c];
      }
    } else {
      const float* src = (const float*)kvv + ((size_t)batch * NKV + kt * BK) * DM;
#pragma unroll
      for (int i = 0; i < 8; ++i) {
        int v = tid + i * 256;
        int r = v >> 5;
        int c = (v & 31) << 3;
        const float* sp = src + r * DM + c;
        float4 f0 = *(const float4*)(sp);
        float4 f1 = *(const float4*)(sp + 4);
        bf16x8 o; ushort* op = (ushort*)&o;
        op[0]=f2bf(f0.x); op[1]=f2bf(f0.y); op[2]=f2bf(f0.z); op[3]=f2bf(f0.w);
        op[4]=f2bf(f1.x); op[5]=f2bf(f1.y); op[6]=f2bf(f1.z); op[7]=f2bf(f1.w);
        *(bf16x8*)&ks[r * KPAD + c] = o;
      }
    }
    __syncthreads();

    // ---- S = Q @ K^T (unscaled) : 16x64 per wave ----
    floatx4 s[4];
#pragma unroll
    for (int nt = 0; nt < 4; ++nt) {
      floatx4 a = (floatx4){0.f, 0.f, 0.f, 0.f};
#pragma unroll
      for (int kb = 0; kb < 8; ++kb) {
        bf16x8 bfr = *(const bf16x8*)&ks[(nt * 16 + l16) * KPAD + kb * 32 + quad * 8];
        a = __builtin_amdgcn_mfma_f32_16x16x32_bf16(qf[kb], bfr, a, 0, 0, 0);
      }
      s[nt] = a;
    }

    // ---- build vs: thread owns d-pair (d0,d0+1) x 4 kv-octets ----
    // dword reads grab (d0,d0+1) of two rows 528B apart (ds_read2-fusable);
    // halves repacked in VALU; b128 writes hit 8 distinct bank slots.
    {
      const int d0 = (tid & 127) << 1;
      const int o0 = tid >> 7;            // 0 or 1
#pragma unroll
      for (int t = 0; t < 4; ++t) {
        const int oct = o0 + t * 2;       // kv-octet 0..7
        const ushort* kp = ks + (oct << 3) * KPAD + d0;
        uint x0 = *(const uint*)(kp);
        uint y0 = *(const uint*)(kp + KPAD);
        uint x1 = *(const uint*)(kp + 2 * KPAD);
        uint y1 = *(const uint*)(kp + 3 * KPAD);
        uint x2 = *(const uint*)(kp + 4 * KPAD);
        uint y2 = *(const uint*)(kp + 5 * KPAD);
        uint x3 = *(const uint*)(kp + 6 * KPAD);
        uint y3 = *(const uint*)(kp + 7 * KPAD);
        uint4 glo, ghi;
        glo.x = (x0 & 0xFFFFu) | (y0 << 16);
        glo.y = (x1 & 0xFFFFu) | (y1 << 16);
        glo.z = (x2 & 0xFFFFu) | (y2 << 16);
        glo.w = (x3 & 0xFFFFu) | (y3 << 16);
        ghi.x = (x0 >> 16) | (y0 & 0xFFFF0000u);
        ghi.y = (x1 >> 16) | (y1 & 0xFFFF0000u);
        ghi.z = (x2 >> 16) | (y2 & 0xFFFF0000u);
        ghi.w = (x3 >> 16) | (y3 & 0xFFFF0000u);
        *(uint4*)&vs[vsoff(d0,     oct)] = glo;
        *(uint4*)&vs[vsoff(d0 + 1, oct)] = ghi;
      }
    }

    // ---- online softmax (DPP reductions, deferred rescale) ----
    float mx4[4];
#pragma unroll
    for (int r = 0; r < 4; ++r) {
      float mx = fmaxf(fmaxf(s[0][r], s[1][r]), fmaxf(s[2][r], s[3][r]));
      mx4[r] = red16_max(mx);
    }
    float grow = fmaxf(fmaxf(mx4[0] - m_i[0], mx4[1] - m_i[1]),
                       fmaxf(mx4[2] - m_i[2], mx4[3] - m_i[3]));
    if (__any(grow > THRU)) {
#pragma unroll
      for (int r = 0; r < 4; ++r) {
        float mnew  = fmaxf(m_i[r], mx4[r]);
        float alpha = exp2f(fmaxf((m_i[r] - mnew) * SCL, -126.f));
        l_i[r] *= alpha;
        m_i[r]  = mnew;
#pragma unroll
        for (int nt = 0; nt < 16; ++nt) acc[nt][r] *= alpha;
      }
    }
    float pv[4][4];  // [nt][r]
#pragma unroll
    for (int r = 0; r < 4; ++r) {
      float rs = 0.f;
#pragma unroll
      for (int nt = 0; nt < 4; ++nt) {
        float p = exp2f((s[nt][r] - m_i[r]) * SCL);
        pv[nt][r] = p;
        rs += p;
      }
      l_i[r] += red16_sum(rs);
    }

    // ---- P: C-layout regs -> LDS -> A-layout frags ----
    ushort* pw = ps + wave * 16 * PPAD;
#pragma unroll
    for (int nt = 0; nt < 4; ++nt)
#pragma unroll
      for (int r = 0; r < 4; ++r)
        pw[(quad * 4 + r) * PPAD + nt * 16 + l16] = f2bf(pv[nt][r]);
    __syncthreads();   // ps ready AND vs fully built

    bf16x8 pf[2];
#pragma unroll
    for (int kf = 0; kf < 2; ++kf)
      pf[kf] = *(const bf16x8*)&pw[l16 * PPAD + kf * 32 + quad * 8];

    // ---- O += P @ V : b[j] = V[k=kf*32+quad*8+j][n=nt*16+l16] via vs b128 ----
#pragma unroll
    for (int nt = 0; nt < 16; ++nt) {
      const ushort* vb = vs + (nt << 10) + vbase;
      bf16x8 v0 = *(const bf16x8*)(vb + sl0);
      acc[nt] = __builtin_amdgcn_mfma_f32_16x16x32_bf16(pf[0], v0, acc[nt], 0, 0, 0);
      bf16x8 v1 = *(const bf16x8*)(vb + sl1);
      acc[nt] = __builtin_amdgcn_mfma_f32_16x16x32_bf16(pf[1], v1, acc[nt], 0, 0, 0);
    }
  }

  // ---- epilogue: O / l, store in the REFERENCE dtype ----
#pragma unroll
  for (int r = 0; r < 4; ++r) l_i[r] = 1.f / l_i[r];
  if constexpr (IS_BF16) {
    ushort* ob = (ushort*)outv + ((size_t)(batch * NQ + q0 + quad * 4)) * DM + l16;
#pragma unroll
    for (int nt = 0; nt < 16; ++nt)
#pragma unroll
      for (int r = 0; r < 4; ++r)
        ob[(size_t)r * DM + nt * 16] = f2bf(acc[nt][r] * l_i[r]);
  } else {
    float* ob = (float*)outv + ((size_t)(batch * NQ + q0 + quad * 4)) * DM + l16;
#pragma unroll
    for (int nt = 0; nt < 16; ++nt)
#pragma unroll
      for (int r = 0; r < 4; ++r)
        ob[(size_t)r * DM + nt * 16] = acc[nt][r] * l_i[r];
  }
}

__global__ __launch_bounds__(256, 2) void attn_fwd(
    const void* __restrict__ qv, const void* __restrict__ kvv,
    void* __restrict__ outv, const int* __restrict__ flag)
{
  __shared__ ushort ks[BK * KPAD];           // kv tile, row-major padded (~33KB)
  __shared__ ushort vs[BK * DM];             // granule-transposed V copy (32KB)
  __shared__ ushort ps[4 * 16 * PPAD];       // per-wave P staging (~9KB)

  if (flag[0] != 0)  // block-uniform: barrier-safe
    attn_body<true >(qv, kvv, outv, ks, vs, ps);
  else
    attn_body<false>(qv, kvv, outv, ks, vs, ps);
}

extern "C" void kernel_launch(void* const* d_in, const int* in_sizes, int n_in,
                              void* d_out, int out_size, void* d_ws, size_t ws_size,
                              hipStream_t stream) {
  const void* q  = d_in[0];
  const void* kv = d_in[1];
  int* flag      = (int*)d_ws;

  detect_dtype<<<dim3(1), dim3(256), 0, stream>>>((const unsigned int*)q, flag);

  dim3 grid(NQ / BQ, NB);
  attn_fwd<<<grid, dim3(256), 0, stream>>>(q, kv, d_out, flag);
}